// Round 1
// baseline (825.155 us; speedup 1.0000x reference)
//
#include <hip/hip_runtime.h>

// Haar level-1 'high' reconstruction: out = x - mean(2x2 block).
// x: [B,C,H,W] fp32 contiguous, H=W=512, B=8, C=64.
// Flattened: R = B*C*H = 262144 rows of W=512 floats.
// One thread per (row-pair, 4-col group): 2 float4 loads, 2 float4 stores.
// Memory-bound: 1.074 GB total traffic -> ~170 us floor at 6.3 TB/s.

constexpr int W   = 512;
constexpr int WV4 = W / 4;  // 128 float4 per row

__global__ __launch_bounds__(256) void haar_high_kernel(
    const float4* __restrict__ x, float4* __restrict__ out, int n_work) {
    int t = blockIdx.x * blockDim.x + threadIdx.x;
    if (t >= n_work) return;

    int pair = t >> 7;        // which row pair (t / WV4)
    int grp  = t & (WV4 - 1); // which float4 within the row

    long long base0 = (long long)pair * (2 * WV4) + grp; // row 2*pair
    long long base1 = base0 + WV4;                       // row 2*pair+1

    float4 a = x[base0];
    float4 b = x[base1];

    float m0 = (a.x + a.y + b.x + b.y) * 0.25f; // left 2x2 block mean
    float m1 = (a.z + a.w + b.z + b.w) * 0.25f; // right 2x2 block mean

    float4 oa = make_float4(a.x - m0, a.y - m0, a.z - m1, a.w - m1);
    float4 ob = make_float4(b.x - m0, b.y - m0, b.z - m1, b.w - m1);

    out[base0] = oa;
    out[base1] = ob;
}

extern "C" void kernel_launch(void* const* d_in, const int* in_sizes, int n_in,
                              void* d_out, int out_size, void* d_ws, size_t ws_size,
                              hipStream_t stream) {
    const float* x = (const float*)d_in[0];
    float* o = (float*)d_out;

    long long total = (long long)in_sizes[0]; // 134,217,728 floats
    int n_work = (int)(total / 8);            // 8 floats per thread -> 16,777,216

    int block = 256;
    int grid  = (n_work + block - 1) / block;
    haar_high_kernel<<<grid, block, 0, stream>>>(
        (const float4*)x, (float4*)o, n_work);
}